// Round 4
// baseline (204404.150 us; speedup 1.0000x reference)
//
#include <hip/hip_runtime.h>

// ResidualSkipRNNForecaster — MI355X weight-register-stationary, chain-multiplexed.
//
// 16 groups x 16 blocks x 512 threads; each group serves 8 chains. Each block
// owns 32 output columns of every matrix, held as fp32 in REGISTERS for the
// whole kernel (zero weight re-streaming; round-2's 5.5us/step L2 stream term
// eliminated). Per step a group runs 16 chain-layer "slots":
//   slots 0..7  : (chain c, layer 0), slots 8..15 : (chain c, layer 1)
// LN folded (exchange PRE-LN v2 + per-block sum/sumsq; h=(v2-mu)*r*g+be is
// linear in v2; weights pre-scaled by feeding gamma; u/q const vectors).
// All-to-all exchange between the 16 blocks via d_ws slots, monotone token
// flags, agent-scope release/acquire (validated in round 2). Gathers are
// issued 4 slots ahead of consumption (publish->consume gap is 8 slots),
// hiding IOD round-trip latency under other chains' compute.
//
// ROUND-4 FIX: round 3 under-allocated the slots region (1 MB) while the
// addressing uses blk*8KB over 256 blocks = 2 MB -> blocks 128..255 published
// payload ON TOP of the flags array (flags read as huge uints -> spins never
// waited -> stale gathers -> absmax 0.219). Layout now: cvec 16KB | slots 2MB
// | flags 32KB. Kernel code unchanged from round 3.
//
// Thread map: tid = ks*32 + cl; ks in [0,16) = k-slice of 32, cl in [0,32) =
// local column. Per-thread registers: w0[32] (g0.*Wh0), wA[32] (g0.*Wi1),
// wB[32] (g1.*Wh1), wx[4] (Wi0) -> 100 VGPRs. Partials via LDS part[16][32].

#define T_SZ 1024
#define DD   64
#define HH   512
#define NCH  8          // chains per group
#define NBLK 16         // blocks per group
#define COLS 32         // columns per block

__device__ __forceinline__ unsigned long long packf2(float a, float b) {
  return (unsigned long long)__float_as_uint(a) |
         ((unsigned long long)__float_as_uint(b) << 32);
}
__device__ __forceinline__ float unpack_lo(unsigned long long u) {
  return __uint_as_float((unsigned)u);
}
__device__ __forceinline__ float unpack_hi(unsigned long long u) {
  return __uint_as_float((unsigned)(u >> 32));
}
__device__ __forceinline__ void st_rlx(unsigned long long* p, unsigned long long v) {
  __hip_atomic_store(p, v, __ATOMIC_RELAXED, __HIP_MEMORY_SCOPE_AGENT);
}
__device__ __forceinline__ unsigned long long ld_rlx(unsigned long long* p) {
  return __hip_atomic_load(p, __ATOMIC_RELAXED, __HIP_MEMORY_SCOPE_AGENT);
}

__global__ void prep_kernel(const float* __restrict__ Wh0, const float* __restrict__ Wi1,
                            const float* __restrict__ Wh1,
                            const float* __restrict__ bi0, const float* __restrict__ bh0,
                            const float* __restrict__ bi1, const float* __restrict__ bh1,
                            const float* __restrict__ g0, const float* __restrict__ be0,
                            const float* __restrict__ g1, const float* __restrict__ be1,
                            float* __restrict__ cvec, unsigned* __restrict__ flags) {
  int g = blockIdx.x * blockDim.x + threadIdx.x;
  if (g < HH) {
    float uw0 = 0.f, qw0 = 0.f, uw1 = 0.f, qw1 = 0.f, uh1 = 0.f, qh1 = 0.f;
    for (int j = 0; j < HH; ++j) {
      float a = Wh0[j * HH + g], b = Wi1[j * HH + g], d = Wh1[j * HH + g];
      uw0 += g0[j] * a; qw0 += be0[j] * a;
      uw1 += g0[j] * b; qw1 += be0[j] * b;
      uh1 += g1[j] * d; qh1 += be1[j] * d;
    }
    float b0 = bi0[g] + bh0[g], b1 = bi1[g] + bh1[g];
    cvec[0 * HH + g] = b0 + qw0;        // c0 full (t>0)
    cvec[1 * HH + g] = b0;              // c0 init (t==0)
    cvec[2 * HH + g] = b1 + qw1 + qh1;  // c1 full
    cvec[3 * HH + g] = b1 + qw1;        // c1 init
    cvec[4 * HH + g] = uw0;
    cvec[5 * HH + g] = uw1;
    cvec[6 * HH + g] = uh1;
  }
  if (g < 256) flags[g * 32] = 0;       // token flags, 128B apart
}

__global__ __launch_bounds__(512, 2) void rnn_group(
    const float* __restrict__ x,
    const float* __restrict__ Wi0, const float* __restrict__ Wh0,
    const float* __restrict__ Wi1, const float* __restrict__ Wh1,
    const float* __restrict__ cvec,
    const float* __restrict__ g0v, const float* __restrict__ be0v,
    const float* __restrict__ g1v, const float* __restrict__ be1v,
    const float* __restrict__ wfc, const float* __restrict__ bfc,
    unsigned long long* __restrict__ slots, unsigned* __restrict__ flags,
    float* __restrict__ out) {
  const int blk   = blockIdx.x;
  const int group = blk >> 4;
  const int p     = blk & 15;          // member index in group
  const int tid   = threadIdx.x;
  const int ks    = tid >> 5;          // 0..15
  const int cl    = tid & 31;          // 0..31
  const int colbase = p * COLS;
  const int col   = colbase + cl;      // this thread's owned column (epilogue)

  // ---------- LDS ----------
  __shared__ __align__(16) float a0[NCH][HH];     // v2_0 buffers (16 KB)
  __shared__ __align__(16) float a1[NCH][HH];     // v2_1 buffers (16 KB)
  __shared__ __align__(16) float xs[NCH][DD];     // x_t per chain (2 KB)
  __shared__ __align__(16) float partH[16][COLS]; // 2 KB
  __shared__ __align__(16) float partX[16][COLS]; // 2 KB
  __shared__ float2 st0[NCH][NBLK];               // (S,Q) partials v2_0 (1 KB)
  __shared__ float2 st1[NCH][NBLK];               // v2_1 (1 KB)
  __shared__ float wredH[8];

  // ---------- per-thread weight registers (fp32, gamma-folded) ----------
  float w0[32], wA[32], wB[32], wx[4];
#pragma unroll
  for (int j = 0; j < 32; ++j) {
    const int k = ks * 32 + j;
    const float gk0 = g0v[k], gk1 = g1v[k];
    w0[j] = gk0 * Wh0[(size_t)k * HH + col];
    wA[j] = gk0 * Wi1[(size_t)k * HH + col];
    wB[j] = gk1 * Wh1[(size_t)k * HH + col];
  }
#pragma unroll
  for (int j = 0; j < 4; ++j) wx[j] = Wi0[(size_t)(ks * 4 + j) * HH + col];

  // per-col epilogue constants
  const float c0f = cvec[col],          c0i = cvec[HH + col];
  const float c1f = cvec[2 * HH + col], c1i = cvec[3 * HH + col];
  const float uw0 = cvec[4 * HH + col], uw1 = cvec[5 * HH + col];
  const float uh1 = cvec[6 * HH + col];
  const float g0c = g0v[col], be0c = be0v[col];
  const float g1c = g1v[col], be1c = be1v[col];

  // zero-init buffers (t=0 feedback terms are multiplied by r_prev = 0,
  // but values must be finite)
  for (int i = tid; i < NCH * HH; i += 512) { (&a0[0][0])[i] = 0.f; (&a1[0][0])[i] = 0.f; }
  // x_0 for all chains
  { const int c = tid >> 6, d = tid & 63;
    xs[c][d] = x[((size_t)(group * NCH + c) * T_SZ) * DD + d]; }
  __syncthreads();

  unsigned long long* myslotbase = slots + (size_t)blk * (NBLK * 2 * 32);

  for (int t = 0; t < T_SZ; ++t) {
    for (int s = 0; s < 16; ++s) {
      const int c = s & 7;
      const bool isL0 = (s < 8);

      // ================= phase A: matmul partials =================
      if (isL0) {
        float h0 = 0.f, h1 = 0.f, h2 = 0.f, h3 = 0.f;
        const float4* av = (const float4*)&a0[c][ks * 32];
#pragma unroll
        for (int q4 = 0; q4 < 8; ++q4) {
          float4 v = av[q4];
          h0 = fmaf(w0[q4 * 4 + 0], v.x, h0);
          h1 = fmaf(w0[q4 * 4 + 1], v.y, h1);
          h2 = fmaf(w0[q4 * 4 + 2], v.z, h2);
          h3 = fmaf(w0[q4 * 4 + 3], v.w, h3);
        }
        float4 xv = *(const float4*)&xs[c][ks * 4];
        float ax = wx[0] * xv.x;
        ax = fmaf(wx[1], xv.y, ax);
        ax = fmaf(wx[2], xv.z, ax);
        ax = fmaf(wx[3], xv.w, ax);
        partH[ks][cl] = (h0 + h1) + (h2 + h3);
        partX[ks][cl] = ax;
      } else {
        float A0 = 0.f, A1 = 0.f, A2 = 0.f, A3 = 0.f;
        float B0 = 0.f, B1 = 0.f, B2 = 0.f, B3 = 0.f;
        const float4* avA = (const float4*)&a0[c][ks * 32];
        const float4* avB = (const float4*)&a1[c][ks * 32];
#pragma unroll
        for (int q4 = 0; q4 < 8; ++q4) {
          float4 va = avA[q4];
          float4 vb = avB[q4];
          A0 = fmaf(wA[q4 * 4 + 0], va.x, A0);
          A1 = fmaf(wA[q4 * 4 + 1], va.y, A1);
          A2 = fmaf(wA[q4 * 4 + 2], va.z, A2);
          A3 = fmaf(wA[q4 * 4 + 3], va.w, A3);
          B0 = fmaf(wB[q4 * 4 + 0], vb.x, B0);
          B1 = fmaf(wB[q4 * 4 + 1], vb.y, B1);
          B2 = fmaf(wB[q4 * 4 + 2], vb.z, B2);
          B3 = fmaf(wB[q4 * 4 + 3], vb.w, B3);
        }
        partH[ks][cl] = (A0 + A1) + (A2 + A3);   // Wi1 part (scale r0)
        partX[ks][cl] = (B0 + B1) + (B2 + B3);   // Wh1 part (scale r1p)
      }
      __syncthreads();   // B1: partials visible

      // ================= phase B: epilogue (tid<32) + gather + x-prefetch ==
      if (tid < 32) {
        float sH = 0.f, sX = 0.f;
#pragma unroll
        for (int i = 0; i < 16; ++i) { sH += partH[i][cl]; sX += partX[i][cl]; }
        float z, prev, hprev, v2;
        if (isL0) {
          float m0p = 0.f, r0p = 0.f;
          if (t > 0) {
            float S = 0.f, Q = 0.f;
#pragma unroll
            for (int i = 0; i < NBLK; ++i) { float2 sq = st0[c][i]; S += sq.x; Q += sq.y; }
            m0p = S * (1.f / HH);
            r0p = 1.f / sqrtf(Q * (1.f / HH) - m0p * m0p + 1e-5f);
          }
          z = ((t == 0) ? c0i : c0f) + r0p * sH - r0p * m0p * uw0 + sX;
          prev = a0[c][col];
          hprev = (t == 0) ? 0.f : (prev - m0p) * r0p * g0c + be0c;
          v2 = tanhf(z) + hprev;
          a0[c][col] = v2;
        } else {
          float S0 = 0.f, Q0 = 0.f;
#pragma unroll
          for (int i = 0; i < NBLK; ++i) { float2 sq = st0[c][i]; S0 += sq.x; Q0 += sq.y; }
          float m0 = S0 * (1.f / HH);
          float r0 = 1.f / sqrtf(Q0 * (1.f / HH) - m0 * m0 + 1e-5f);
          float m1p = 0.f, r1p = 0.f;
          if (t > 0) {
            float S = 0.f, Q = 0.f;
#pragma unroll
            for (int i = 0; i < NBLK; ++i) { float2 sq = st1[c][i]; S += sq.x; Q += sq.y; }
            m1p = S * (1.f / HH);
            r1p = 1.f / sqrtf(Q * (1.f / HH) - m1p * m1p + 1e-5f);
          }
          z = ((t == 0) ? c1i : c1f) + r0 * sH - r0 * m0 * uw1 + r1p * sX - r1p * m1p * uh1;
          prev = a1[c][col];
          hprev = (t == 0) ? 0.f : (prev - m1p) * r1p * g1c + be1c;
          v2 = tanhf(z) + hprev;
          a1[c][col] = v2;
        }
        // publish payload: pairs by even lanes
        unsigned long long* myslot = myslotbase + (size_t)(c * 2 + (isL0 ? 0 : 1)) * 32;
        float v2n = __shfl_down(v2, 1);
        if ((cl & 1) == 0) st_rlx(myslot + (cl >> 1), packf2(v2, v2n));
        float sS = v2, sQ = v2 * v2;
#pragma unroll
        for (int off = 16; off; off >>= 1) { sS += __shfl_down(sS, off); sQ += __shfl_down(sQ, off); }
        if (cl == 0) {
          st_rlx(myslot + 16, packf2(sS, sQ));
          if (isL0) st0[c][p] = make_float2(sS, sQ);
          else      st1[c][p] = make_float2(sS, sQ);
        }
      } else if (tid >= 64 && tid < 319) {
        // -------- gather for consume-slot s+4 (data published at slot s-4) --
        if (t > 0 || s >= 4) {
          const unsigned thr = (unsigned)(t * 16 + s - 3);
          int cp, php;
          if (s < 4)        { cp = s + 4;  php = 1; }
          else if (s < 12)  { cp = s - 4;  php = 0; }
          else              { cp = s - 12; php = 1; }
          if (tid < 304) {
            const int idx = tid - 64;              // 0..239
            const int pbi = idx >> 4;              // 0..14
            const int j   = idx & 15;
            const int pl  = pbi + (pbi >= p ? 1 : 0);
            const int pglob = group * NBLK + pl;
            unsigned* pf = flags + pglob * 32;
            while (__hip_atomic_load(pf, __ATOMIC_ACQUIRE, __HIP_MEMORY_SCOPE_AGENT) < thr)
              __builtin_amdgcn_s_sleep(1);
            unsigned long long u =
                ld_rlx(slots + ((size_t)pglob * (NBLK * 2) + cp * 2 + php) * 32 + j);
            float* buf = php ? &a1[cp][0] : &a0[cp][0];
            buf[pl * 32 + 2 * j]     = unpack_lo(u);
            buf[pl * 32 + 2 * j + 1] = unpack_hi(u);
          } else {
            const int pbi = tid - 304;             // 0..14
            const int pl  = pbi + (pbi >= p ? 1 : 0);
            const int pglob = group * NBLK + pl;
            unsigned* pf = flags + pglob * 32;
            while (__hip_atomic_load(pf, __ATOMIC_ACQUIRE, __HIP_MEMORY_SCOPE_AGENT) < thr)
              __builtin_amdgcn_s_sleep(1);
            unsigned long long u =
                ld_rlx(slots + ((size_t)pglob * (NBLK * 2) + cp * 2 + php) * 32 + 16);
            if (php) st1[cp][pl] = make_float2(unpack_lo(u), unpack_hi(u));
            else     st0[cp][pl] = make_float2(unpack_lo(u), unpack_hi(u));
          }
        }
      } else if (tid >= 320 && tid < 384) {
        // -------- x prefetch for step t+1, chain s-8 --------
        if (s >= 8 && t + 1 < T_SZ) {
          const int cx = s - 8, d = tid - 320;
          xs[cx][d] = x[((size_t)(group * NCH + cx) * T_SZ + (t + 1)) * DD + d];
        }
      }
      __syncthreads();   // B2: drains payload stores (vmcnt 0) + LDS visible
      if (tid == 0)
        __hip_atomic_store(flags + blk * 32, (unsigned)(t * 16 + s + 1),
                           __ATOMIC_RELEASE, __HIP_MEMORY_SCOPE_AGENT);
    }
  }

  // ================= head (group leaders): out = LN(v2_1^{T-1}).Wfc + bfc ==
  if (p == 0) {
    if (tid < NBLK) {
      unsigned* pf = flags + (group * NBLK + tid) * 32;
      while (__hip_atomic_load(pf, __ATOMIC_ACQUIRE, __HIP_MEMORY_SCOPE_AGENT) <
             (unsigned)(T_SZ * 16))
        __builtin_amdgcn_s_sleep(1);
    }
    __syncthreads();
    for (int c = 0; c < NCH; ++c) {
      if (tid < 256) {
        const int pl = tid >> 4, j = tid & 15;
        unsigned long long u =
            ld_rlx(slots + ((size_t)(group * NBLK + pl) * (NBLK * 2) + c * 2 + 1) * 32 + j);
        a1[0][pl * 32 + 2 * j]     = unpack_lo(u);
        a1[0][pl * 32 + 2 * j + 1] = unpack_hi(u);
      } else if (tid < 272) {
        const int pl = tid - 256;
        unsigned long long u =
            ld_rlx(slots + ((size_t)(group * NBLK + pl) * (NBLK * 2) + c * 2 + 1) * 32 + 16);
        st1[0][pl] = make_float2(unpack_lo(u), unpack_hi(u));
      }
      __syncthreads();
      float S = 0.f, Q = 0.f;
#pragma unroll
      for (int i = 0; i < NBLK; ++i) { float2 sq = st1[0][i]; S += sq.x; Q += sq.y; }
      float mu = S * (1.f / HH);
      float r  = 1.f / sqrtf(Q * (1.f / HH) - mu * mu + 1e-5f);
      float h  = (a1[0][tid] - mu) * r * g1v[tid] + be1v[tid];
      float v  = h * wfc[tid];
#pragma unroll
      for (int off = 32; off; off >>= 1) v += __shfl_down(v, off);
      if ((tid & 63) == 0) wredH[tid >> 6] = v;
      __syncthreads();
      if (tid == 0) {
        float T = 0.f;
#pragma unroll
        for (int w = 0; w < 8; ++w) T += wredH[w];
        out[group * NCH + c] = T + bfc[0];
      }
      __syncthreads();
    }
  }
}

extern "C" void kernel_launch(void* const* d_in, const int* in_sizes, int n_in,
                              void* d_out, int out_size, void* d_ws, size_t ws_size,
                              hipStream_t stream) {
  const float* x   = (const float*)d_in[0];
  const float* Wi0 = (const float*)d_in[1];
  const float* bi0 = (const float*)d_in[2];
  const float* Wh0 = (const float*)d_in[3];
  const float* bh0 = (const float*)d_in[4];
  const float* g0  = (const float*)d_in[5];
  const float* be0 = (const float*)d_in[6];
  const float* Wi1 = (const float*)d_in[7];
  const float* bi1 = (const float*)d_in[8];
  const float* Wh1 = (const float*)d_in[9];
  const float* bh1 = (const float*)d_in[10];
  const float* g1  = (const float*)d_in[11];
  const float* be1 = (const float*)d_in[12];
  const float* Wfc = (const float*)d_in[13];
  const float* bfc = (const float*)d_in[14];
  float* out = (float*)d_out;

  // ws layout: cvec 16 KB | slots 2 MB (256 blocks x 1024 x 8B) | flags 32 KB
  char* ws = (char*)d_ws;
  float* cvec               = (float*)(ws);
  unsigned long long* slots = (unsigned long long*)(ws + 16384);
  unsigned* flags           = (unsigned*)(ws + 16384 + 2097152);

  prep_kernel<<<256, 256, 0, stream>>>(Wh0, Wi1, Wh1, bi0, bh0, bi1, bh1,
                                       g0, be0, g1, be1, cvec, flags);
  rnn_group<<<256, 512, 0, stream>>>(x, Wi0, Wh0, Wi1, Wh1, cvec,
                                     g0, be0, g1, be1, Wfc, bfc,
                                     slots, flags, out);
}

// Round 5
// 16717.946 us; speedup vs baseline: 12.2266x; 12.2266x over previous
//
#include <hip/hip_runtime.h>

// ResidualSkipRNNForecaster — MI355X register-stationary weights + MFMA + coarse exchange.
//
// 16 groups x 16 blocks x 512 threads; group serves 8 chains. Block owns 32
// output cols; weights live in bf16 MFMA B-fragments in VGPRs (48 regs) for
// the whole kernel -> zero weight streaming (R4's validated core idea).
// Per step, 3 MFMA phases ([8x512]@[512x32] each = 32 mfma_16x16x32_bf16):
//   A: z0 = x@Wi0 + v2_0^{t-1}@(g0.*Wh0)   (LN folded, R2-validated algebra)
//   B: v2_1^{t-1}@(g1.*Wh1)                 (input gathered with 1-step slack)
//   C: v2_0^t@(g0.*Wi1)                     (input = this step's A exchange)
// Activations stored bf16 in LDS (a0bf/a1bf, 16 rows: 8 chains + 8 zero-pad
// for the M=16 MFMA tile) -> A-frags are direct ds_read_b128. Residual +
// LN stats stay fp32 (v2prev in registers, (S,Q) exchanged fp32).
//
// R4 lesson: 16 lockstep slots/step = 16K fabric rendezvous -> 204 ms.
// Now: 5 barriers/step, ONE blocking exchange (v2_0^t, covered by phase B),
// 15 pollers + LDS ready-token instead of 240 remote spinners, parity
// double-buffered payload slots (no reuse races).

#define T_SZ 1024
#define DD   64
#define HH   512
#define NCH  8
#define NBLK 16

typedef __attribute__((ext_vector_type(8))) short short8;
typedef __attribute__((ext_vector_type(4))) float f32x4;
typedef unsigned long long ull;

__device__ __forceinline__ unsigned short f2b(float f) {
  unsigned u = __float_as_uint(f);
  u += 0x7fffu + ((u >> 16) & 1u);   // RNE
  return (unsigned short)(u >> 16);
}
__device__ __forceinline__ float b2f(unsigned short s) {
  return __uint_as_float(((unsigned)s) << 16);
}
__device__ __forceinline__ ull packf2(float a, float b) {
  return (ull)__float_as_uint(a) | ((ull)__float_as_uint(b) << 32);
}
__device__ __forceinline__ float unpack_lo(ull u) { return __uint_as_float((unsigned)u); }
__device__ __forceinline__ float unpack_hi(ull u) { return __uint_as_float((unsigned)(u >> 32)); }
__device__ __forceinline__ void st_rlx(ull* p, ull v) {
  __hip_atomic_store(p, v, __ATOMIC_RELAXED, __HIP_MEMORY_SCOPE_AGENT);
}
__device__ __forceinline__ ull ld_rlx(const ull* p) {
  return __hip_atomic_load(p, __ATOMIC_RELAXED, __HIP_MEMORY_SCOPE_AGENT);
}

__global__ void prep_kernel(const float* __restrict__ Wh0, const float* __restrict__ Wi1,
                            const float* __restrict__ Wh1,
                            const float* __restrict__ bi0, const float* __restrict__ bh0,
                            const float* __restrict__ bi1, const float* __restrict__ bh1,
                            const float* __restrict__ g0, const float* __restrict__ be0,
                            const float* __restrict__ g1, const float* __restrict__ be1,
                            float* __restrict__ cvec, unsigned* __restrict__ flags) {
  int g = blockIdx.x * blockDim.x + threadIdx.x;
  if (g < HH) {
    float uw0 = 0.f, qw0 = 0.f, uw1 = 0.f, qw1 = 0.f, uh1 = 0.f, qh1 = 0.f;
    for (int j = 0; j < HH; ++j) {
      float a = Wh0[j * HH + g], b = Wi1[j * HH + g], d = Wh1[j * HH + g];
      uw0 += g0[j] * a; qw0 += be0[j] * a;
      uw1 += g0[j] * b; qw1 += be0[j] * b;
      uh1 += g1[j] * d; qh1 += be1[j] * d;
    }
    float b0 = bi0[g] + bh0[g], b1 = bi1[g] + bh1[g];
    cvec[0 * HH + g] = b0 + qw0;        // c0 full (t>0)
    cvec[1 * HH + g] = b0;              // c0 init (t==0)
    cvec[2 * HH + g] = b1 + qw1 + qh1;  // c1 full
    cvec[3 * HH + g] = b1 + qw1;        // c1 init
    cvec[4 * HH + g] = uw0;
    cvec[5 * HH + g] = uw1;
    cvec[6 * HH + g] = uh1;
  }
  if (g < 4096) flags[g] = 0;           // 256 blocks x 16 words (A at +0, B at +8)
}

__global__ __launch_bounds__(512, 1) void rnn_mfma(
    const float* __restrict__ x,
    const float* __restrict__ Wi0, const float* __restrict__ Wh0,
    const float* __restrict__ Wi1, const float* __restrict__ Wh1,
    const float* __restrict__ cvec,
    const float* __restrict__ g0v, const float* __restrict__ be0v,
    const float* __restrict__ g1v, const float* __restrict__ be1v,
    const float* __restrict__ wfc, const float* __restrict__ bfc,
    ull* __restrict__ pay, ull* __restrict__ pst,
    unsigned* __restrict__ flags, float* __restrict__ out) {

  const int blk = blockIdx.x, group = blk >> 4, p = blk & 15;
  const int tid = threadIdx.x;
  const int wave = tid >> 6, lane = tid & 63;
  const int quad = lane >> 4, m16 = lane & 15;

  // row stride 536 bf16 = 268 words: 16B-aligned rows, banks spread (268%32=12)
  __shared__ unsigned short a0bf[16][536];   // bf16 v2_0 (rows 8..15 = 0 pad)
  __shared__ unsigned short a1bf[16][536];   // bf16 v2_1
  __shared__ unsigned short xsb[2][16][72];  // bf16 x_t, parity buffered
  __shared__ float parts[8][8][33];          // MFMA partials (phases A & C)
  __shared__ float partsB[8][8][33];         // phase B partials
  __shared__ float partsX[2][8][33];         // x@Wi0 partials (waves 0,1)
  __shared__ float2 st0[NCH][NBLK];          // (S,Q) per publisher, layer 0
  __shared__ float2 st1[NCH][NBLK];          // layer 1
  __shared__ int rdy0s, rdy1s;
  volatile int* rdy0 = &rdy0s;
  volatile int* rdy1 = &rdy1s;

  // ---------------- init ----------------
  for (int i = tid; i < 16 * 536; i += 512) {
    (&a0bf[0][0])[i] = 0; (&a1bf[0][0])[i] = 0;
  }
  for (int i = tid; i < 2 * 16 * 72; i += 512) (&xsb[0][0][0])[i] = 0;
  if (tid == 0) { rdy0s = 0; rdy1s = 0; }
  { // x_0: thread (wave=chain, lane=d)
    float xv = x[((size_t)(group * NCH + wave) * T_SZ) * DD + lane];
    xsb[0][wave][lane] = f2b(xv);
  }

  // ---------------- static weight B-fragments (bf16, gamma-folded) --------
  // B[k][n]: lane supplies W[k = quad*8+j within 32-K window][n = m16]
  short8 wf0[2][2], wfA[2][2], wfB[2][2], wfx[2];
#pragma unroll
  for (int n = 0; n < 2; ++n)
#pragma unroll
    for (int j = 0; j < 8; ++j) wfx[n][j] = 0;
#pragma unroll
  for (int s = 0; s < 2; ++s)
#pragma unroll
    for (int n = 0; n < 2; ++n) {
      const int col = p * 32 + n * 16 + m16;
#pragma unroll
      for (int j = 0; j < 8; ++j) {
        const int k = wave * 64 + s * 32 + quad * 8 + j;
        wf0[s][n][j] = (short)f2b(g0v[k] * Wh0[(size_t)k * HH + col]);
        wfA[s][n][j] = (short)f2b(g0v[k] * Wi1[(size_t)k * HH + col]);
        wfB[s][n][j] = (short)f2b(g1v[k] * Wh1[(size_t)k * HH + col]);
      }
    }
  if (wave < 2) {
#pragma unroll
    for (int n = 0; n < 2; ++n) {
      const int col = p * 32 + n * 16 + m16;
#pragma unroll
      for (int j = 0; j < 8; ++j)
        wfx[n][j] = (short)f2b(Wi0[(size_t)(wave * 32 + quad * 8 + j) * HH + col]);
    }
  }

  // epilogue constants (threads of waves 0-3: chain = 2*wave + lane/32, col)
  const int cl   = lane & 31;
  const int ech  = 2 * wave + (lane >> 5);
  const int col_e = p * 32 + cl;
  const float c0f = cvec[col_e],          c0i = cvec[HH + col_e];
  const float c1f = cvec[2 * HH + col_e], c1i = cvec[3 * HH + col_e];
  const float uw0 = cvec[4 * HH + col_e], uw1 = cvec[5 * HH + col_e];
  const float uh1 = cvec[6 * HH + col_e];
  const float g0c = g0v[col_e], be0c = be0v[col_e];
  const float g1c = g1v[col_e], be1c = be1v[col_e];

  float v2prev0 = 0.f, v2prev1 = 0.f;
  __syncthreads();

  for (int t = 0; t < T_SZ; ++t) {
    const int par = t & 1;

    // ================= phase A : L0 MFMAs =================
    {
      f32x4 acc0 = {0.f, 0.f, 0.f, 0.f}, acc1 = {0.f, 0.f, 0.f, 0.f};
#pragma unroll
      for (int s = 0; s < 2; ++s) {
        const short8 af = *(const short8*)&a0bf[m16][wave * 64 + s * 32 + quad * 8];
        acc0 = __builtin_amdgcn_mfma_f32_16x16x32_bf16(af, wf0[s][0], acc0, 0, 0, 0);
        acc1 = __builtin_amdgcn_mfma_f32_16x16x32_bf16(af, wf0[s][1], acc1, 0, 0, 0);
      }
      if (lane < 32) {    // D: chain = quad*4+reg (chains 0..7), coltile n
#pragma unroll
        for (int r = 0; r < 4; ++r) {
          parts[wave][quad * 4 + r][m16]      = acc0[r];
          parts[wave][quad * 4 + r][16 + m16] = acc1[r];
        }
      }
      if (wave < 2) {
        f32x4 ax0 = {0.f, 0.f, 0.f, 0.f}, ax1 = {0.f, 0.f, 0.f, 0.f};
        const short8 xf = *(const short8*)&xsb[par][m16][wave * 32 + quad * 8];
        ax0 = __builtin_amdgcn_mfma_f32_16x16x32_bf16(xf, wfx[0], ax0, 0, 0, 0);
        ax1 = __builtin_amdgcn_mfma_f32_16x16x32_bf16(xf, wfx[1], ax1, 0, 0, 0);
        if (lane < 32) {
#pragma unroll
          for (int r = 0; r < 4; ++r) {
            partsX[wave][quad * 4 + r][m16]      = ax0[r];
            partsX[wave][quad * 4 + r][16 + m16] = ax1[r];
          }
        }
      }
    }
    __syncthreads();                                    // b1

    // ==== A-epilogue (waves 0-3) | gather v2_1^{t-1} (waves 4-7) ====
    if (wave < 4) {
      float sH = 0.f;
#pragma unroll
      for (int w = 0; w < 8; ++w) sH += parts[w][ech][cl];
      const float sX = partsX[0][ech][cl] + partsX[1][ech][cl];
      float m0p = 0.f, r0p = 0.f;
      if (t > 0) {
        float S = 0.f, Q = 0.f;
#pragma unroll
        for (int i = 0; i < NBLK; ++i) { float2 sq = st0[ech][i]; S += sq.x; Q += sq.y; }
        m0p = S * (1.f / HH);
        r0p = 1.f / sqrtf(Q * (1.f / HH) - m0p * m0p + 1e-5f);
      }
      const float z = ((t == 0) ? c0i : c0f) + r0p * sH - r0p * m0p * uw0 + sX;
      const float h0prev = (t == 0) ? 0.f : (v2prev0 - m0p) * r0p * g0c + be0c;
      const float v2 = tanhf(z) + h0prev;
      v2prev0 = v2;
      const unsigned vb = f2b(v2);
      a0bf[ech][p * 32 + cl] = (unsigned short)vb;
      const unsigned u01 = vb | (__shfl_down(vb, 1) << 16);
      const unsigned u23 = __shfl_down(u01, 2);
      if ((cl & 3) == 0)
        st_rlx(pay + ((((size_t)blk * 2 + 0) * 2 + par) * NCH + ech) * 8 + (cl >> 2),
               (ull)u01 | ((ull)u23 << 32));
      float S = v2, Q = v2 * v2;
#pragma unroll
      for (int off = 16; off; off >>= 1) {
        S += __shfl_down(S, off, 32); Q += __shfl_down(Q, off, 32);
      }
      if (cl == 0) {
        st0[ech][p] = make_float2(S, Q);
        st_rlx(pst + (((size_t)blk * 2 + 0) * 2 + par) * NCH + ech, packf2(S, Q));
      }
    } else if (t > 0) {
      if (wave == 4) {
        if (lane < 15) {
          const int pl = lane + (lane >= p);
          unsigned* pf = flags + (group * NBLK + pl) * 16 + 8;
          while (__hip_atomic_load(pf, __ATOMIC_ACQUIRE, __HIP_MEMORY_SCOPE_AGENT) < (unsigned)t)
            __builtin_amdgcn_s_sleep(1);
        }
        if (lane == 0) *rdy1 = t;
      }
      while (*rdy1 < t) __builtin_amdgcn_s_sleep(1);
      const int par1 = (t - 1) & 1;
      const int base = (wave - 4) * 64 + lane;          // 0..255
#pragma unroll
      for (int it = 0; it < 5; ++it) {
        const int item = base + it * 256;
        if (item < 15 * 72) {
          const int pi = item / 72, rem = item - pi * 72;
          const int pl = pi + (pi >= p);
          const size_t pb = ((size_t)(group * NBLK + pl) * 2 + 1) * 2 + par1;
          if (rem < 64) {
            const int ch = rem >> 3, j = rem & 7;
            ull u = ld_rlx(pay + (pb * NCH + ch) * 8 + j);
            *(ull*)&a1bf[ch][pl * 32 + 4 * j] = u;
          } else {
            const int ch = rem - 64;
            ull u = ld_rlx(pst + pb * NCH + ch);
            st1[ch][pl] = make_float2(unpack_lo(u), unpack_hi(u));
          }
        }
      }
    }
    __syncthreads();                                    // b2 (drains publishes)
    if (tid == 0)
      __hip_atomic_store(flags + blk * 16, (unsigned)(t + 1),
                         __ATOMIC_RELEASE, __HIP_MEMORY_SCOPE_AGENT);

    // ================= phase B : Wh1 MFMAs + x prefetch =================
    float xv = 0.f;
    if (t + 1 < T_SZ)
      xv = x[((size_t)(group * NCH + wave) * T_SZ + (t + 1)) * DD + lane];
    {
      f32x4 acc0 = {0.f, 0.f, 0.f, 0.f}, acc1 = {0.f, 0.f, 0.f, 0.f};
#pragma unroll
      for (int s = 0; s < 2; ++s) {
        const short8 af = *(const short8*)&a1bf[m16][wave * 64 + s * 32 + quad * 8];
        acc0 = __builtin_amdgcn_mfma_f32_16x16x32_bf16(af, wfB[s][0], acc0, 0, 0, 0);
        acc1 = __builtin_amdgcn_mfma_f32_16x16x32_bf16(af, wfB[s][1], acc1, 0, 0, 0);
      }
      if (lane < 32) {
#pragma unroll
        for (int r = 0; r < 4; ++r) {
          partsB[wave][quad * 4 + r][m16]      = acc0[r];
          partsB[wave][quad * 4 + r][16 + m16] = acc1[r];
        }
      }
    }
    if (t + 1 < T_SZ) xsb[(t + 1) & 1][wave][lane] = f2b(xv);

    // -------- gather v2_0^t (the one blocking exchange) --------
    if (tid < 15) {
      const int pl = tid + (tid >= p);
      unsigned* pf = flags + (group * NBLK + pl) * 16;
      while (__hip_atomic_load(pf, __ATOMIC_ACQUIRE, __HIP_MEMORY_SCOPE_AGENT) < (unsigned)(t + 1))
        __builtin_amdgcn_s_sleep(1);
    }
    if (tid == 0) *rdy0 = t + 1;
    while (*rdy0 < t + 1) __builtin_amdgcn_s_sleep(1);
#pragma unroll
    for (int it = 0; it < 3; ++it) {
      const int item = tid + it * 512;
      if (item < 15 * 72) {
        const int pi = item / 72, rem = item - pi * 72;
        const int pl = pi + (pi >= p);
        const size_t pb = ((size_t)(group * NBLK + pl) * 2 + 0) * 2 + par;
        if (rem < 64) {
          const int ch = rem >> 3, j = rem & 7;
          ull u = ld_rlx(pay + (pb * NCH + ch) * 8 + j);
          *(ull*)&a0bf[ch][pl * 32 + 4 * j] = u;
        } else {
          const int ch = rem - 64;
          ull u = ld_rlx(pst + pb * NCH + ch);
          st0[ch][pl] = make_float2(unpack_lo(u), unpack_hi(u));
        }
      }
    }
    __syncthreads();                                    // b3

    // ================= phase C : Wi1 MFMAs =================
    {
      f32x4 acc0 = {0.f, 0.f, 0.f, 0.f}, acc1 = {0.f, 0.f, 0.f, 0.f};
#pragma unroll
      for (int s = 0; s < 2; ++s) {
        const short8 af = *(const short8*)&a0bf[m16][wave * 64 + s * 32 + quad * 8];
        acc0 = __builtin_amdgcn_mfma_f32_16x16x32_bf16(af, wfA[s][0], acc0, 0, 0, 0);
        acc1 = __builtin_amdgcn_mfma_f32_16x16x32_bf16(af, wfA[s][1], acc1, 0, 0, 0);
      }
      if (lane < 32) {
#pragma unroll
        for (int r = 0; r < 4; ++r) {
          parts[wave][quad * 4 + r][m16]      = acc0[r];
          parts[wave][quad * 4 + r][16 + m16] = acc1[r];
        }
      }
    }
    __syncthreads();                                    // b4

    // ============ C-epilogue (waves 0-3) ============
    if (wave < 4) {
      float sB = 0.f, sC = 0.f;
#pragma unroll
      for (int w = 0; w < 8; ++w) { sB += partsB[w][ech][cl]; sC += parts[w][ech][cl]; }
      float S0 = 0.f, Q0 = 0.f;
#pragma unroll
      for (int i = 0; i < NBLK; ++i) { float2 sq = st0[ech][i]; S0 += sq.x; Q0 += sq.y; }
      const float m0 = S0 * (1.f / HH);
      const float r0 = 1.f / sqrtf(Q0 * (1.f / HH) - m0 * m0 + 1e-5f);
      float m1p = 0.f, r1p = 0.f;
      if (t > 0) {
        float S = 0.f, Q = 0.f;
#pragma unroll
        for (int i = 0; i < NBLK; ++i) { float2 sq = st1[ech][i]; S += sq.x; Q += sq.y; }
        m1p = S * (1.f / HH);
        r1p = 1.f / sqrtf(Q * (1.f / HH) - m1p * m1p + 1e-5f);
      }
      const float z = ((t == 0) ? c1i : c1f) + r0 * sC - r0 * m0 * uw1
                      + r1p * sB - r1p * m1p * uh1;
      const float h1prev = (t == 0) ? 0.f : (v2prev1 - m1p) * r1p * g1c + be1c;
      const float v2 = tanhf(z) + h1prev;
      v2prev1 = v2;
      const unsigned vb = f2b(v2);
      a1bf[ech][p * 32 + cl] = (unsigned short)vb;
      const unsigned u01 = vb | (__shfl_down(vb, 1) << 16);
      const unsigned u23 = __shfl_down(u01, 2);
      if ((cl & 3) == 0)
        st_rlx(pay + ((((size_t)blk * 2 + 1) * 2 + par) * NCH + ech) * 8 + (cl >> 2),
               (ull)u01 | ((ull)u23 << 32));
      float S = v2, Q = v2 * v2;
#pragma unroll
      for (int off = 16; off; off >>= 1) {
        S += __shfl_down(S, off, 32); Q += __shfl_down(Q, off, 32);
      }
      if (cl == 0) {
        st1[ech][p] = make_float2(S, Q);
        st_rlx(pst + (((size_t)blk * 2 + 1) * 2 + par) * NCH + ech, packf2(S, Q));
      }
    }
    __syncthreads();                                    // b5 (drains publishes)
    if (tid == 0)
      __hip_atomic_store(flags + blk * 16 + 8, (unsigned)(t + 1),
                         __ATOMIC_RELEASE, __HIP_MEMORY_SCOPE_AGENT);
  }

  // ============ head (p==0 blocks): out = LN(v2_1^{T-1}).Wfc + bfc ========
  if (p == 0) {
    if (tid < 16) {
      unsigned* pf = flags + (group * NBLK + tid) * 16 + 8;
      while (__hip_atomic_load(pf, __ATOMIC_ACQUIRE, __HIP_MEMORY_SCOPE_AGENT) < (unsigned)T_SZ)
        __builtin_amdgcn_s_sleep(1);
    }
    __syncthreads();
    const int c = wave;   // wave handles chain c
    ull su = 0;
    if (lane < 16)
      su = ld_rlx(pst + (((size_t)(group * NBLK + lane) * 2 + 1) * 2 + 1) * NCH + c);
    float S = unpack_lo(su), Q = unpack_hi(su);
#pragma unroll
    for (int off = 32; off; off >>= 1) { S += __shfl_down(S, off); Q += __shfl_down(Q, off); }
    S = __shfl(S, 0); Q = __shfl(Q, 0);
    const float m1 = S * (1.f / HH);
    const float r1 = 1.f / sqrtf(Q * (1.f / HH) - m1 * m1 + 1e-5f);
    float o = 0.f;
#pragma unroll
    for (int it = 0; it < 2; ++it) {
      const int j2 = lane * 2 + it, pl = j2 >> 3, j = j2 & 7;
      ull u = ld_rlx(pay + ((((size_t)(group * NBLK + pl) * 2 + 1) * 2 + 1) * NCH + c) * 8 + j);
#pragma unroll
      for (int q = 0; q < 4; ++q) {
        const int col = pl * 32 + 4 * j + q;
        const float h = (b2f((unsigned short)(u >> (16 * q))) - m1) * r1 * g1v[col] + be1v[col];
        o += h * wfc[col];
      }
    }
#pragma unroll
    for (int off = 32; off; off >>= 1) o += __shfl_down(o, off);
    if (lane == 0) out[group * NCH + c] = o + bfc[0];
  }
}

extern "C" void kernel_launch(void* const* d_in, const int* in_sizes, int n_in,
                              void* d_out, int out_size, void* d_ws, size_t ws_size,
                              hipStream_t stream) {
  const float* x   = (const float*)d_in[0];
  const float* Wi0 = (const float*)d_in[1];
  const float* bi0 = (const float*)d_in[2];
  const float* Wh0 = (const float*)d_in[3];
  const float* bh0 = (const float*)d_in[4];
  const float* g0  = (const float*)d_in[5];
  const float* be0 = (const float*)d_in[6];
  const float* Wi1 = (const float*)d_in[7];
  const float* bi1 = (const float*)d_in[8];
  const float* Wh1 = (const float*)d_in[9];
  const float* bh1 = (const float*)d_in[10];
  const float* g1  = (const float*)d_in[11];
  const float* be1 = (const float*)d_in[12];
  const float* Wfc = (const float*)d_in[13];
  const float* bfc = (const float*)d_in[14];
  float* out = (float*)d_out;

  // ws: cvec 16KB | pay 512KB (256 blk x 2 layer x 2 parity x 8 ch x 8 ull)
  //     | pst 64KB | flags 16KB  -> ~608KB total
  char* ws = (char*)d_ws;
  float* cvec     = (float*)(ws);
  ull* pay        = (ull*)(ws + 16384);
  ull* pst        = (ull*)(ws + 16384 + 524288);
  unsigned* flags = (unsigned*)(ws + 16384 + 524288 + 65536);

  prep_kernel<<<256, 256, 0, stream>>>(Wh0, Wi1, Wh1, bi0, bh0, bi1, bh1,
                                       g0, be0, g1, be1, cvec, flags);
  rnn_mfma<<<256, 512, 0, stream>>>(x, Wi0, Wh0, Wi1, Wh1, cvec,
                                    g0, be0, g1, be1, Wfc, bfc,
                                    pay, pst, flags, out);
}

// Round 6
// 7397.585 us; speedup vs baseline: 27.6312x; 2.2599x over previous
//
#include <hip/hip_runtime.h>

// ResidualSkipRNNForecaster — MI355X register-stationary weights + MFMA + coarse exchange.
//
// 16 groups x 16 blocks x 512 threads; group serves 8 chains. Block owns 32
// output cols; weights live in bf16 MFMA B-fragments in VGPRs (48 regs) for
// the whole kernel -> zero weight streaming. Per step, 3 MFMA phases:
//   A: z0 = x@Wi0 + v2_0^{t-1}@(g0.*Wh0)   (LN folded)
//   B: v2_1^{t-1}@(g1.*Wh1)                 (input gathered with 1-step slack)
//   C: v2_0^t@(g0.*Wi1)                     (input = this step's A exchange)
//
// R5 lesson: the ONE blocking rendezvous cost ~14us/step with ACQUIRE polls.
// Agent-scope acquire loads emit buffer_inv (invalidate XCD-L2 shared lines)
// EVERY poll iteration x 15 pollers x 256 blocks -> chip-wide invalidate
// storm (R4: 240 spinners -> 12.5us/slot; R2: 2 spinners -> ~5us; scaling
// matches). R6 change: ALL polls are RELAXED (no cache maintenance; relaxed
// agent atomics bypass L2 and read the coherent point), flag stores RELAXED
// behind the __syncthreads vmcnt(0) drain (+ compiler-only memory barrier).
// Payload was already relaxed-atomic. Zero buffer_inv/wbl2 in steady state.

#define T_SZ 1024
#define DD   64
#define HH   512
#define NCH  8
#define NBLK 16

typedef __attribute__((ext_vector_type(8))) short short8;
typedef __attribute__((ext_vector_type(4))) float f32x4;
typedef unsigned long long ull;

__device__ __forceinline__ unsigned short f2b(float f) {
  unsigned u = __float_as_uint(f);
  u += 0x7fffu + ((u >> 16) & 1u);   // RNE
  return (unsigned short)(u >> 16);
}
__device__ __forceinline__ float b2f(unsigned short s) {
  return __uint_as_float(((unsigned)s) << 16);
}
__device__ __forceinline__ ull packf2(float a, float b) {
  return (ull)__float_as_uint(a) | ((ull)__float_as_uint(b) << 32);
}
__device__ __forceinline__ float unpack_lo(ull u) { return __uint_as_float((unsigned)u); }
__device__ __forceinline__ float unpack_hi(ull u) { return __uint_as_float((unsigned)(u >> 32)); }
__device__ __forceinline__ void st_rlx(ull* p, ull v) {
  __hip_atomic_store(p, v, __ATOMIC_RELAXED, __HIP_MEMORY_SCOPE_AGENT);
}
__device__ __forceinline__ ull ld_rlx(const ull* p) {
  return __hip_atomic_load(p, __ATOMIC_RELAXED, __HIP_MEMORY_SCOPE_AGENT);
}
__device__ __forceinline__ unsigned ld_flag(const unsigned* p) {
  return __hip_atomic_load(p, __ATOMIC_RELAXED, __HIP_MEMORY_SCOPE_AGENT);
}
__device__ __forceinline__ void st_flag(unsigned* p, unsigned v) {
  asm volatile("" ::: "memory");   // keep store after the preceding barrier
  __hip_atomic_store(p, v, __ATOMIC_RELAXED, __HIP_MEMORY_SCOPE_AGENT);
}

__global__ void prep_kernel(const float* __restrict__ Wh0, const float* __restrict__ Wi1,
                            const float* __restrict__ Wh1,
                            const float* __restrict__ bi0, const float* __restrict__ bh0,
                            const float* __restrict__ bi1, const float* __restrict__ bh1,
                            const float* __restrict__ g0, const float* __restrict__ be0,
                            const float* __restrict__ g1, const float* __restrict__ be1,
                            float* __restrict__ cvec, unsigned* __restrict__ flags) {
  int g = blockIdx.x * blockDim.x + threadIdx.x;
  if (g < HH) {
    float uw0 = 0.f, qw0 = 0.f, uw1 = 0.f, qw1 = 0.f, uh1 = 0.f, qh1 = 0.f;
    for (int j = 0; j < HH; ++j) {
      float a = Wh0[j * HH + g], b = Wi1[j * HH + g], d = Wh1[j * HH + g];
      uw0 += g0[j] * a; qw0 += be0[j] * a;
      uw1 += g0[j] * b; qw1 += be0[j] * b;
      uh1 += g1[j] * d; qh1 += be1[j] * d;
    }
    float b0 = bi0[g] + bh0[g], b1 = bi1[g] + bh1[g];
    cvec[0 * HH + g] = b0 + qw0;        // c0 full (t>0)
    cvec[1 * HH + g] = b0;              // c0 init (t==0)
    cvec[2 * HH + g] = b1 + qw1 + qh1;  // c1 full
    cvec[3 * HH + g] = b1 + qw1;        // c1 init
    cvec[4 * HH + g] = uw0;
    cvec[5 * HH + g] = uw1;
    cvec[6 * HH + g] = uh1;
  }
  if (g < 4096) flags[g] = 0;           // 256 blocks x 16 words (A at +0, B at +8)
}

__global__ __launch_bounds__(512, 1) void rnn_mfma(
    const float* __restrict__ x,
    const float* __restrict__ Wi0, const float* __restrict__ Wh0,
    const float* __restrict__ Wi1, const float* __restrict__ Wh1,
    const float* __restrict__ cvec,
    const float* __restrict__ g0v, const float* __restrict__ be0v,
    const float* __restrict__ g1v, const float* __restrict__ be1v,
    const float* __restrict__ wfc, const float* __restrict__ bfc,
    ull* __restrict__ pay, ull* __restrict__ pst,
    unsigned* __restrict__ flags, float* __restrict__ out) {

  const int blk = blockIdx.x, group = blk >> 4, p = blk & 15;
  const int tid = threadIdx.x;
  const int wave = tid >> 6, lane = tid & 63;
  const int quad = lane >> 4, m16 = lane & 15;

  // row stride 536 bf16 = 268 words: 16B-aligned rows, banks spread (268%32=12)
  __shared__ unsigned short a0bf[16][536];   // bf16 v2_0 (rows 8..15 = 0 pad)
  __shared__ unsigned short a1bf[16][536];   // bf16 v2_1
  __shared__ unsigned short xsb[2][16][72];  // bf16 x_t, parity buffered
  __shared__ float parts[8][8][33];          // MFMA partials (phases A & C)
  __shared__ float partsB[8][8][33];         // phase B partials
  __shared__ float partsX[2][8][33];         // x@Wi0 partials (waves 0,1)
  __shared__ float2 st0[NCH][NBLK];          // (S,Q) per publisher, layer 0
  __shared__ float2 st1[NCH][NBLK];          // layer 1
  __shared__ int rdy0s, rdy1s;
  volatile int* rdy0 = &rdy0s;
  volatile int* rdy1 = &rdy1s;

  // ---------------- init ----------------
  for (int i = tid; i < 16 * 536; i += 512) {
    (&a0bf[0][0])[i] = 0; (&a1bf[0][0])[i] = 0;
  }
  for (int i = tid; i < 2 * 16 * 72; i += 512) (&xsb[0][0][0])[i] = 0;
  if (tid == 0) { rdy0s = 0; rdy1s = 0; }
  { // x_0: thread (wave=chain, lane=d)
    float xv = x[((size_t)(group * NCH + wave) * T_SZ) * DD + lane];
    xsb[0][wave][lane] = f2b(xv);
  }

  // ---------------- static weight B-fragments (bf16, gamma-folded) --------
  short8 wf0[2][2], wfA[2][2], wfB[2][2], wfx[2];
#pragma unroll
  for (int n = 0; n < 2; ++n)
#pragma unroll
    for (int j = 0; j < 8; ++j) wfx[n][j] = 0;
#pragma unroll
  for (int s = 0; s < 2; ++s)
#pragma unroll
    for (int n = 0; n < 2; ++n) {
      const int col = p * 32 + n * 16 + m16;
#pragma unroll
      for (int j = 0; j < 8; ++j) {
        const int k = wave * 64 + s * 32 + quad * 8 + j;
        wf0[s][n][j] = (short)f2b(g0v[k] * Wh0[(size_t)k * HH + col]);
        wfA[s][n][j] = (short)f2b(g0v[k] * Wi1[(size_t)k * HH + col]);
        wfB[s][n][j] = (short)f2b(g1v[k] * Wh1[(size_t)k * HH + col]);
      }
    }
  if (wave < 2) {
#pragma unroll
    for (int n = 0; n < 2; ++n) {
      const int col = p * 32 + n * 16 + m16;
#pragma unroll
      for (int j = 0; j < 8; ++j)
        wfx[n][j] = (short)f2b(Wi0[(size_t)(wave * 32 + quad * 8 + j) * HH + col]);
    }
  }

  // epilogue constants (threads of waves 0-3: chain = 2*wave + lane/32, col)
  const int cl   = lane & 31;
  const int ech  = 2 * wave + (lane >> 5);
  const int col_e = p * 32 + cl;
  const float c0f = cvec[col_e],          c0i = cvec[HH + col_e];
  const float c1f = cvec[2 * HH + col_e], c1i = cvec[3 * HH + col_e];
  const float uw0 = cvec[4 * HH + col_e], uw1 = cvec[5 * HH + col_e];
  const float uh1 = cvec[6 * HH + col_e];
  const float g0c = g0v[col_e], be0c = be0v[col_e];
  const float g1c = g1v[col_e], be1c = be1v[col_e];

  float v2prev0 = 0.f, v2prev1 = 0.f;
  __syncthreads();

  for (int t = 0; t < T_SZ; ++t) {
    const int par = t & 1;

    // ================= phase A : L0 MFMAs =================
    {
      f32x4 acc0 = {0.f, 0.f, 0.f, 0.f}, acc1 = {0.f, 0.f, 0.f, 0.f};
#pragma unroll
      for (int s = 0; s < 2; ++s) {
        const short8 af = *(const short8*)&a0bf[m16][wave * 64 + s * 32 + quad * 8];
        acc0 = __builtin_amdgcn_mfma_f32_16x16x32_bf16(af, wf0[s][0], acc0, 0, 0, 0);
        acc1 = __builtin_amdgcn_mfma_f32_16x16x32_bf16(af, wf0[s][1], acc1, 0, 0, 0);
      }
      if (lane < 32) {
#pragma unroll
        for (int r = 0; r < 4; ++r) {
          parts[wave][quad * 4 + r][m16]      = acc0[r];
          parts[wave][quad * 4 + r][16 + m16] = acc1[r];
        }
      }
      if (wave < 2) {
        f32x4 ax0 = {0.f, 0.f, 0.f, 0.f}, ax1 = {0.f, 0.f, 0.f, 0.f};
        const short8 xf = *(const short8*)&xsb[par][m16][wave * 32 + quad * 8];
        ax0 = __builtin_amdgcn_mfma_f32_16x16x32_bf16(xf, wfx[0], ax0, 0, 0, 0);
        ax1 = __builtin_amdgcn_mfma_f32_16x16x32_bf16(xf, wfx[1], ax1, 0, 0, 0);
        if (lane < 32) {
#pragma unroll
          for (int r = 0; r < 4; ++r) {
            partsX[wave][quad * 4 + r][m16]      = ax0[r];
            partsX[wave][quad * 4 + r][16 + m16] = ax1[r];
          }
        }
      }
    }
    __syncthreads();                                    // b1

    // ==== A-epilogue (waves 0-3) | gather v2_1^{t-1} (waves 4-7) ====
    if (wave < 4) {
      float sH = 0.f;
#pragma unroll
      for (int w = 0; w < 8; ++w) sH += parts[w][ech][cl];
      const float sX = partsX[0][ech][cl] + partsX[1][ech][cl];
      float m0p = 0.f, r0p = 0.f;
      if (t > 0) {
        float S = 0.f, Q = 0.f;
#pragma unroll
        for (int i = 0; i < NBLK; ++i) { float2 sq = st0[ech][i]; S += sq.x; Q += sq.y; }
        m0p = S * (1.f / HH);
        r0p = 1.f / sqrtf(Q * (1.f / HH) - m0p * m0p + 1e-5f);
      }
      const float z = ((t == 0) ? c0i : c0f) + r0p * sH - r0p * m0p * uw0 + sX;
      const float h0prev = (t == 0) ? 0.f : (v2prev0 - m0p) * r0p * g0c + be0c;
      const float v2 = tanhf(z) + h0prev;
      v2prev0 = v2;
      const unsigned vb = f2b(v2);
      a0bf[ech][p * 32 + cl] = (unsigned short)vb;
      const unsigned u01 = vb | (__shfl_down(vb, 1) << 16);
      const unsigned u23 = __shfl_down(u01, 2);
      if ((cl & 3) == 0)
        st_rlx(pay + ((((size_t)blk * 2 + 0) * 2 + par) * NCH + ech) * 8 + (cl >> 2),
               (ull)u01 | ((ull)u23 << 32));
      float S = v2, Q = v2 * v2;
#pragma unroll
      for (int off = 16; off; off >>= 1) {
        S += __shfl_down(S, off, 32); Q += __shfl_down(Q, off, 32);
      }
      if (cl == 0) {
        st0[ech][p] = make_float2(S, Q);
        st_rlx(pst + (((size_t)blk * 2 + 0) * 2 + par) * NCH + ech, packf2(S, Q));
      }
    } else if (t > 0) {
      if (wave == 4) {
        if (lane < 15) {
          const int pl = lane + (lane >= p);
          const unsigned* pf = flags + (group * NBLK + pl) * 16 + 8;
          while (ld_flag(pf) < (unsigned)t) __builtin_amdgcn_s_sleep(1);
        }
        if (lane == 0) *rdy1 = t;
      }
      while (*rdy1 < t) __builtin_amdgcn_s_sleep(1);
      const int par1 = (t - 1) & 1;
      const int base = (wave - 4) * 64 + lane;          // 0..255
#pragma unroll
      for (int it = 0; it < 5; ++it) {
        const int item = base + it * 256;
        if (item < 15 * 72) {
          const int pi = item / 72, rem = item - pi * 72;
          const int pl = pi + (pi >= p);
          const size_t pb = ((size_t)(group * NBLK + pl) * 2 + 1) * 2 + par1;
          if (rem < 64) {
            const int ch = rem >> 3, j = rem & 7;
            ull u = ld_rlx(pay + (pb * NCH + ch) * 8 + j);
            *(ull*)&a1bf[ch][pl * 32 + 4 * j] = u;
          } else {
            const int ch = rem - 64;
            ull u = ld_rlx(pst + pb * NCH + ch);
            st1[ch][pl] = make_float2(unpack_lo(u), unpack_hi(u));
          }
        }
      }
    }
    __syncthreads();                                    // b2 (drains publishes)
    if (tid == 0) st_flag(flags + blk * 16, (unsigned)(t + 1));

    // ================= phase B : Wh1 MFMAs + x prefetch =================
    float xv = 0.f;
    if (t + 1 < T_SZ)
      xv = x[((size_t)(group * NCH + wave) * T_SZ + (t + 1)) * DD + lane];
    {
      f32x4 acc0 = {0.f, 0.f, 0.f, 0.f}, acc1 = {0.f, 0.f, 0.f, 0.f};
#pragma unroll
      for (int s = 0; s < 2; ++s) {
        const short8 af = *(const short8*)&a1bf[m16][wave * 64 + s * 32 + quad * 8];
        acc0 = __builtin_amdgcn_mfma_f32_16x16x32_bf16(af, wfB[s][0], acc0, 0, 0, 0);
        acc1 = __builtin_amdgcn_mfma_f32_16x16x32_bf16(af, wfB[s][1], acc1, 0, 0, 0);
      }
      if (lane < 32) {
#pragma unroll
        for (int r = 0; r < 4; ++r) {
          partsB[wave][quad * 4 + r][m16]      = acc0[r];
          partsB[wave][quad * 4 + r][16 + m16] = acc1[r];
        }
      }
    }
    if (t + 1 < T_SZ) xsb[(t + 1) & 1][wave][lane] = f2b(xv);

    // -------- gather v2_0^t (the one blocking exchange) --------
    if (tid < 15) {
      const int pl = tid + (tid >= p);
      const unsigned* pf = flags + (group * NBLK + pl) * 16;
      while (ld_flag(pf) < (unsigned)(t + 1)) __builtin_amdgcn_s_sleep(1);
    }
    if (tid == 0) *rdy0 = t + 1;
    while (*rdy0 < t + 1) __builtin_amdgcn_s_sleep(1);
#pragma unroll
    for (int it = 0; it < 3; ++it) {
      const int item = tid + it * 512;
      if (item < 15 * 72) {
        const int pi = item / 72, rem = item - pi * 72;
        const int pl = pi + (pi >= p);
        const size_t pb = ((size_t)(group * NBLK + pl) * 2 + 0) * 2 + par;
        if (rem < 64) {
          const int ch = rem >> 3, j = rem & 7;
          ull u = ld_rlx(pay + (pb * NCH + ch) * 8 + j);
          *(ull*)&a0bf[ch][pl * 32 + 4 * j] = u;
        } else {
          const int ch = rem - 64;
          ull u = ld_rlx(pst + pb * NCH + ch);
          st0[ch][pl] = make_float2(unpack_lo(u), unpack_hi(u));
        }
      }
    }
    __syncthreads();                                    // b3

    // ================= phase C : Wi1 MFMAs =================
    {
      f32x4 acc0 = {0.f, 0.f, 0.f, 0.f}, acc1 = {0.f, 0.f, 0.f, 0.f};
#pragma unroll
      for (int s = 0; s < 2; ++s) {
        const short8 af = *(const short8*)&a0bf[m16][wave * 64 + s * 32 + quad * 8];
        acc0 = __builtin_amdgcn_mfma_f32_16x16x32_bf16(af, wfA[s][0], acc0, 0, 0, 0);
        acc1 = __builtin_amdgcn_mfma_f32_16x16x32_bf16(af, wfA[s][1], acc1, 0, 0, 0);
      }
      if (lane < 32) {
#pragma unroll
        for (int r = 0; r < 4; ++r) {
          parts[wave][quad * 4 + r][m16]      = acc0[r];
          parts[wave][quad * 4 + r][16 + m16] = acc1[r];
        }
      }
    }
    __syncthreads();                                    // b4

    // ============ C-epilogue (waves 0-3) ============
    if (wave < 4) {
      float sB = 0.f, sC = 0.f;
#pragma unroll
      for (int w = 0; w < 8; ++w) { sB += partsB[w][ech][cl]; sC += parts[w][ech][cl]; }
      float S0 = 0.f, Q0 = 0.f;
#pragma unroll
      for (int i = 0; i < NBLK; ++i) { float2 sq = st0[ech][i]; S0 += sq.x; Q0 += sq.y; }
      const float m0 = S0 * (1.f / HH);
      const float r0 = 1.f / sqrtf(Q0 * (1.f / HH) - m0 * m0 + 1e-5f);
      float m1p = 0.f, r1p = 0.f;
      if (t > 0) {
        float S = 0.f, Q = 0.f;
#pragma unroll
        for (int i = 0; i < NBLK; ++i) { float2 sq = st1[ech][i]; S += sq.x; Q += sq.y; }
        m1p = S * (1.f / HH);
        r1p = 1.f / sqrtf(Q * (1.f / HH) - m1p * m1p + 1e-5f);
      }
      const float z = ((t == 0) ? c1i : c1f) + r0 * sC - r0 * m0 * uw1
                      + r1p * sB - r1p * m1p * uh1;
      const float h1prev = (t == 0) ? 0.f : (v2prev1 - m1p) * r1p * g1c + be1c;
      const float v2 = tanhf(z) + h1prev;
      v2prev1 = v2;
      const unsigned vb = f2b(v2);
      a1bf[ech][p * 32 + cl] = (unsigned short)vb;
      const unsigned u01 = vb | (__shfl_down(vb, 1) << 16);
      const unsigned u23 = __shfl_down(u01, 2);
      if ((cl & 3) == 0)
        st_rlx(pay + ((((size_t)blk * 2 + 1) * 2 + par) * NCH + ech) * 8 + (cl >> 2),
               (ull)u01 | ((ull)u23 << 32));
      float S = v2, Q = v2 * v2;
#pragma unroll
      for (int off = 16; off; off >>= 1) {
        S += __shfl_down(S, off, 32); Q += __shfl_down(Q, off, 32);
      }
      if (cl == 0) {
        st1[ech][p] = make_float2(S, Q);
        st_rlx(pst + (((size_t)blk * 2 + 1) * 2 + par) * NCH + ech, packf2(S, Q));
      }
    }
    __syncthreads();                                    // b5 (drains publishes)
    if (tid == 0) st_flag(flags + blk * 16 + 8, (unsigned)(t + 1));
  }

  // ============ head (p==0 blocks): out = LN(v2_1^{T-1}).Wfc + bfc ========
  if (p == 0) {
    if (tid < 16) {
      const unsigned* pf = flags + (group * NBLK + tid) * 16 + 8;
      while (ld_flag(pf) < (unsigned)T_SZ) __builtin_amdgcn_s_sleep(1);
    }
    __syncthreads();
    const int c = wave;   // wave handles chain c
    ull su = 0;
    if (lane < 16)
      su = ld_rlx(pst + (((size_t)(group * NBLK + lane) * 2 + 1) * 2 + 1) * NCH + c);
    float S = unpack_lo(su), Q = unpack_hi(su);
#pragma unroll
    for (int off = 32; off; off >>= 1) { S += __shfl_down(S, off); Q += __shfl_down(Q, off); }
    S = __shfl(S, 0); Q = __shfl(Q, 0);
    const float m1 = S * (1.f / HH);
    const float r1 = 1.f / sqrtf(Q * (1.f / HH) - m1 * m1 + 1e-5f);
    float o = 0.f;
#pragma unroll
    for (int it = 0; it < 2; ++it) {
      const int j2 = lane * 2 + it, pl = j2 >> 3, j = j2 & 7;
      ull u = ld_rlx(pay + ((((size_t)(group * NBLK + pl) * 2 + 1) * 2 + 1) * NCH + c) * 8 + j);
#pragma unroll
      for (int q = 0; q < 4; ++q) {
        const int col = pl * 32 + 4 * j + q;
        const float h = (b2f((unsigned short)(u >> (16 * q))) - m1) * r1 * g1v[col] + be1v[col];
        o += h * wfc[col];
      }
    }
#pragma unroll
    for (int off = 32; off; off >>= 1) o += __shfl_down(o, off);
    if (lane == 0) out[group * NCH + c] = o + bfc[0];
  }
}

extern "C" void kernel_launch(void* const* d_in, const int* in_sizes, int n_in,
                              void* d_out, int out_size, void* d_ws, size_t ws_size,
                              hipStream_t stream) {
  const float* x   = (const float*)d_in[0];
  const float* Wi0 = (const float*)d_in[1];
  const float* bi0 = (const float*)d_in[2];
  const float* Wh0 = (const float*)d_in[3];
  const float* bh0 = (const float*)d_in[4];
  const float* g0  = (const float*)d_in[5];
  const float* be0 = (const float*)d_in[6];
  const float* Wi1 = (const float*)d_in[7];
  const float* bi1 = (const float*)d_in[8];
  const float* Wh1 = (const float*)d_in[9];
  const float* bh1 = (const float*)d_in[10];
  const float* g1  = (const float*)d_in[11];
  const float* be1 = (const float*)d_in[12];
  const float* Wfc = (const float*)d_in[13];
  const float* bfc = (const float*)d_in[14];
  float* out = (float*)d_out;

  // ws: cvec 16KB | pay 512KB | pst 64KB | flags 16KB
  char* ws = (char*)d_ws;
  float* cvec     = (float*)(ws);
  ull* pay        = (ull*)(ws + 16384);
  ull* pst        = (ull*)(ws + 16384 + 524288);
  unsigned* flags = (unsigned*)(ws + 16384 + 524288 + 65536);

  prep_kernel<<<256, 256, 0, stream>>>(Wh0, Wi1, Wh1, bi0, bh0, bi1, bh1,
                                       g0, be0, g1, be1, cvec, flags);
  rnn_mfma<<<256, 512, 0, stream>>>(x, Wi0, Wh0, Wi1, Wh1, cvec,
                                    g0, be0, g1, be1, Wfc, bfc,
                                    pay, pst, flags, out);
}